// Round 1
// baseline (97.752 us; speedup 1.0000x reference)
//
#include <hip/hip_runtime.h>
#include <hip/hip_bf16.h>

#define F_DIM 512
#define NT 512
#define DEPTH 5
#define NCOL (NT * DEPTH)   // 2560
#define BATCH 2048
#define NLEAF 32

typedef __attribute__((ext_vector_type(8))) short bf16x8;
typedef __attribute__((ext_vector_type(4))) float f32x4;

__device__ __forceinline__ void gl2lds16(const void* g, void* l) {
    __builtin_amdgcn_global_load_lds((const __attribute__((address_space(1))) void*)g,
                                     (__attribute__((address_space(3))) void*)l,
                                     16, 0, 0);
}

// ---------------------------------------------------------------------------
// Kernel 1: column softmax of feat_attention [512][2560] -> Wt bf16 [2560][512]
// (transposed output so the GEMM sees a B^T operand, k-contiguous).
// feat_attention is uniform[0,1) => exp cannot overflow => skip the max pass.
// Block: 256 threads = 16 f-groups x 16 cols. Grid: 2560/16 = 160 blocks.
// ---------------------------------------------------------------------------
__global__ __launch_bounds__(256) void softmax_t(const float* __restrict__ fa,
                                                 __hip_bfloat16* __restrict__ Wt) {
    const int l = threadIdx.x & 15;          // col within block
    const int g = threadIdx.x >> 4;          // f-group 0..15 (32 f each)
    const int col = blockIdx.x * 16 + l;
    const int f0 = g * 32;
    __shared__ float red[16][16];

    float s = 0.f;
    for (int i = 0; i < 32; ++i)
        s += __expf(fa[(size_t)(f0 + i) * NCOL + col]);
    red[g][l] = s;
    __syncthreads();

    float S = 0.f;
#pragma unroll
    for (int gg = 0; gg < 16; ++gg) S += red[gg][l];
    const float inv = 1.0f / S;

    // write pass: Wt[col][f] for f in [f0, f0+32), 8-byte packed stores
    __hip_bfloat16* dst = Wt + (size_t)col * F_DIM + f0;
    for (int i = 0; i < 32; i += 4) {
        union { ushort4 u; __hip_bfloat16 h[4]; } pk;
#pragma unroll
        for (int jj = 0; jj < 4; ++jj) {
            float v = __expf(fa[(size_t)(f0 + i + jj) * NCOL + col]) * inv;
            pk.h[jj] = __float2bfloat16(v);
        }
        *(ushort4*)(dst + i) = pk.u;
    }
}

// ---------------------------------------------------------------------------
// Kernel 2: cast x [2048][512] fp32 -> bf16
// ---------------------------------------------------------------------------
__global__ __launch_bounds__(256) void cast_x(const float* __restrict__ x,
                                              __hip_bfloat16* __restrict__ Xb) {
    const size_t i = (size_t)blockIdx.x * blockDim.x + threadIdx.x;  // per 4 elems
    const float4 v = ((const float4*)x)[i];
    union { ushort4 u; __hip_bfloat16 h[4]; } pk;
    pk.h[0] = __float2bfloat16(v.x);
    pk.h[1] = __float2bfloat16(v.y);
    pk.h[2] = __float2bfloat16(v.z);
    pk.h[3] = __float2bfloat16(v.w);
    ((ushort4*)Xb)[i] = pk.u;
}

// ---------------------------------------------------------------------------
// Kernel 3: GEMM C[2048][2560] = A[2048][512] * Bt[2560][512]^T  (bf16 MFMA)
// 128x128 tile, BK=64, 4 waves in 2x2, each wave 4x4 of 16x16x32 MFMAs.
// global_load_lds width-16 staging; XOR chunk swizzle (applied on the global
// address, since LDS dest is wave-uniform base + lane*16).
// ---------------------------------------------------------------------------
__global__ __launch_bounds__(256) void gemm_bt(const __hip_bfloat16* __restrict__ A,
                                               const __hip_bfloat16* __restrict__ Bt,
                                               float* __restrict__ C) {
    __shared__ __hip_bfloat16 As[128 * 64];
    __shared__ __hip_bfloat16 Bs[128 * 64];

    const int tid = threadIdx.x;
    const int w = tid >> 6;
    const int l = tid & 63;
    const int m0 = blockIdx.y * 128;
    const int n0 = blockIdx.x * 128;
    const int wm = (w & 1) * 64;
    const int wn = (w >> 1) * 64;

    f32x4 acc[4][4] = {};

    const int srow = l >> 3;                    // row within 8-row group
    const int schunk = (l & 7) ^ srow;          // source 16B-chunk (xor swizzle)

    for (int kt = 0; kt < 8; ++kt) {
        const int k0 = kt * 64;
#pragma unroll
        for (int q = 0; q < 4; ++q) {
            const int row = q * 32 + w * 8 + srow;
            gl2lds16(A + ((size_t)(m0 + row) * F_DIM + k0 + schunk * 8),
                     As + (q * 32 + w * 8) * 64);
            gl2lds16(Bt + ((size_t)(n0 + row) * F_DIM + k0 + schunk * 8),
                     Bs + (q * 32 + w * 8) * 64);
        }
        __syncthreads();

#pragma unroll
        for (int ks = 0; ks < 2; ++ks) {
            bf16x8 af[4], bfr[4];
            const int cbase = ks * 4 + (l >> 4);
#pragma unroll
            for (int im = 0; im < 4; ++im) {
                const int r = wm + im * 16 + (l & 15);
                af[im] = *(const bf16x8*)(As + r * 64 + ((cbase ^ (r & 7)) * 8));
            }
#pragma unroll
            for (int in = 0; in < 4; ++in) {
                const int r = wn + in * 16 + (l & 15);
                bfr[in] = *(const bf16x8*)(Bs + r * 64 + ((cbase ^ (r & 7)) * 8));
            }
#pragma unroll
            for (int im = 0; im < 4; ++im)
#pragma unroll
                for (int in = 0; in < 4; ++in)
                    acc[im][in] = __builtin_amdgcn_mfma_f32_16x16x32_bf16(
                        af[im], bfr[in], acc[im][in], 0, 0, 0);
        }
        __syncthreads();
    }

    // epilogue: C/D layout col = lane&15, row = (lane>>4)*4 + reg
    const int cr = (l >> 4) * 4;
    const int cc = l & 15;
#pragma unroll
    for (int im = 0; im < 4; ++im) {
#pragma unroll
        for (int in = 0; in < 4; ++in) {
            float* Cp = C + (size_t)(m0 + wm + im * 16 + cr) * NCOL
                          + (n0 + wn + in * 16 + cc);
#pragma unroll
            for (int r = 0; r < 4; ++r)
                Cp[(size_t)r * NCOL] = acc[im][in][r];
        }
    }
}

// ---------------------------------------------------------------------------
// Kernel 4: tree gating + response contraction.
// fv [2048][2560] (col = n*5+j) -> out [2048][512].
// c1_j = clamp(alpha_j*fv + beta_j, 0, 1); c0 = 1-c1; DP-fold over 5 depths.
// Response staged in LDS transposed with XOR swizzle (conflict-free R/W).
// Block: 512 threads (t = tree n), 8 batch rows per block. Grid: 256.
// ---------------------------------------------------------------------------
__global__ __launch_bounds__(512) void tree_out(const float* __restrict__ fv,
                                                const float* __restrict__ th,
                                                const float* __restrict__ lt,
                                                const float* __restrict__ resp,
                                                float* __restrict__ out) {
    __shared__ float rT[32 * 512];   // rT[i][n^i] = resp[n][i]  (64 KiB exactly)
    const int t = threadIdx.x;       // tree index n

#pragma unroll
    for (int k = 0; k < 32; ++k) {
        const int idx = t + k * 512;     // linear over 512*32
        const int n = idx >> 5, i = idx & 31;
        rT[i * 512 + (n ^ i)] = resp[idx];
    }

    float alpha[DEPTH], beta[DEPTH];
#pragma unroll
    for (int j = 0; j < DEPTH; ++j) {
        const float a = 0.5f * __expf(-lt[t * DEPTH + j]);
        alpha[j] = a;
        beta[j] = 0.5f - th[t * DEPTH + j] * a;
    }
    __syncthreads();

    float r[32];
#pragma unroll
    for (int i = 0; i < 32; ++i) r[i] = rT[i * 512 + (t ^ i)];

    const int b0 = blockIdx.x * 8;
    for (int rr = 0; rr < 8; ++rr) {
        const int b = b0 + rr;
        const float* f = fv + (size_t)b * NCOL + t * DEPTH;
        float c1[DEPTH];
#pragma unroll
        for (int j = 0; j < DEPTH; ++j) {
            const float v = fmaf(alpha[j], f[j], beta[j]);
            c1[j] = fminf(fmaxf(v, 0.f), 1.f);
        }
        float s16[16], s8[8], s4[4], s2[2];
#pragma unroll
        for (int m = 0; m < 16; ++m) s16[m] = fmaf(c1[0], r[2*m+1] - r[2*m], r[2*m]);
#pragma unroll
        for (int m = 0; m < 8; ++m)  s8[m]  = fmaf(c1[1], s16[2*m+1] - s16[2*m], s16[2*m]);
#pragma unroll
        for (int m = 0; m < 4; ++m)  s4[m]  = fmaf(c1[2], s8[2*m+1] - s8[2*m], s8[2*m]);
#pragma unroll
        for (int m = 0; m < 2; ++m)  s2[m]  = fmaf(c1[3], s4[2*m+1] - s4[2*m], s4[2*m]);
        out[(size_t)b * NT + t] = fmaf(c1[4], s2[1] - s2[0], s2[0]);
    }
}

// ---------------------------------------------------------------------------
extern "C" void kernel_launch(void* const* d_in, const int* in_sizes, int n_in,
                              void* d_out, int out_size, void* d_ws, size_t ws_size,
                              hipStream_t stream) {
    const float* x    = (const float*)d_in[0];
    const float* fa   = (const float*)d_in[1];
    const float* th   = (const float*)d_in[2];
    const float* lt   = (const float*)d_in[3];
    const float* resp = (const float*)d_in[4];
    // d_in[5] = path_map: deterministic oblivious layout, hardcoded in tree_out.

    char* ws = (char*)d_ws;
    __hip_bfloat16* Wt = (__hip_bfloat16*)(ws);                 // 2560*512*2 = 2.62 MB
    __hip_bfloat16* Xb = (__hip_bfloat16*)(ws + (4u << 20));    // 2048*512*2 = 2.10 MB
    float*          fv = (float*)(ws + (8u << 20));             // 2048*2560*4 = 21 MB
    float* out = (float*)d_out;

    hipLaunchKernelGGL(softmax_t, dim3(NCOL / 16), dim3(256), 0, stream, fa, Wt);
    hipLaunchKernelGGL(cast_x, dim3((BATCH * F_DIM / 4) / 256), dim3(256), 0, stream, x, Xb);
    hipLaunchKernelGGL(gemm_bt, dim3(NCOL / 128, BATCH / 128), dim3(256), 0, stream, Xb, Wt, fv);
    hipLaunchKernelGGL(tree_out, dim3(BATCH / 8), dim3(512), 0, stream, fv, th, lt, resp, out);
}

// Round 2
// 88.107 us; speedup vs baseline: 1.1095x; 1.1095x over previous
//
#include <hip/hip_runtime.h>
#include <hip/hip_bf16.h>

#define F_DIM 512
#define NT 512
#define DEPTH 5
#define NCOL (NT * DEPTH)   // 2560
#define BATCH 2048

typedef __attribute__((ext_vector_type(8))) short bf16x8;
typedef __attribute__((ext_vector_type(4))) float f32x4;

__device__ __forceinline__ void gl2lds16(const void* g, void* l) {
    __builtin_amdgcn_global_load_lds((const __attribute__((address_space(1))) void*)g,
                                     (__attribute__((address_space(3))) void*)l,
                                     16, 0, 0);
}

// ---------------------------------------------------------------------------
// Kernel 1: prep = cast_x (blocks 0..1023) + column-softmax->Wt (blocks 1024..1183)
// Softmax: single global pass, exp values kept in registers (32/thread).
// fa is uniform[0,1) => exp cannot overflow => skip max subtraction.
// ---------------------------------------------------------------------------
__global__ __launch_bounds__(256) void prep(const float* __restrict__ x,
                                            const float* __restrict__ fa,
                                            __hip_bfloat16* __restrict__ Xb,
                                            __hip_bfloat16* __restrict__ Wt) {
    if (blockIdx.x < 1024) {
        // cast x [2048*512] fp32 -> bf16, float4 per thread
        const size_t i = (size_t)blockIdx.x * 256 + threadIdx.x;
        const float4 v = ((const float4*)x)[i];
        union { ushort4 u; __hip_bfloat16 h[4]; } pk;
        pk.h[0] = __float2bfloat16(v.x);
        pk.h[1] = __float2bfloat16(v.y);
        pk.h[2] = __float2bfloat16(v.z);
        pk.h[3] = __float2bfloat16(v.w);
        ((ushort4*)Xb)[i] = pk.u;
        return;
    }
    const int bx = blockIdx.x - 1024;        // 0..159
    const int l = threadIdx.x & 15;          // col within block
    const int g = threadIdx.x >> 4;          // f-group 0..15 (32 f each)
    const int col = bx * 16 + l;
    const int f0 = g * 32;
    __shared__ float red[16][16];

    float e[32];
    float s = 0.f;
#pragma unroll
    for (int i = 0; i < 32; ++i) {
        e[i] = __expf(fa[(size_t)(f0 + i) * NCOL + col]);
        s += e[i];
    }
    red[g][l] = s;
    __syncthreads();

    float S = 0.f;
#pragma unroll
    for (int gg = 0; gg < 16; ++gg) S += red[gg][l];
    const float inv = 1.0f / S;

    __hip_bfloat16* dst = Wt + (size_t)col * F_DIM + f0;
#pragma unroll
    for (int i = 0; i < 32; i += 4) {
        union { ushort4 u; __hip_bfloat16 h[4]; } pk;
#pragma unroll
        for (int jj = 0; jj < 4; ++jj)
            pk.h[jj] = __float2bfloat16(e[i + jj] * inv);
        *(ushort4*)(dst + i) = pk.u;
    }
}

// ---------------------------------------------------------------------------
// Kernel 2: fused GEMM + tree routing.
// fv_tile[128][160] = Xb[128][512] * Wt[160 cols][512]^T   (bf16 MFMA)
//   tile N=160 = 32 whole trees (5 cols each) -> tree epilogue stays in-block.
// 4 waves in 2x2; wave = 64 rows x 80 cols = 4x5 MFMA tiles of 16x16x32.
// Staging: global_load_lds width-16, XOR chunk swizzle on the global address.
// Epilogue: per im-pass, 32 rows x 160 cols staged to LDS slab (reuses As/Bs),
// then DP-fold (c0 = 1-c1) over 5 depths against per-thread response regs.
// ---------------------------------------------------------------------------
__global__ __launch_bounds__(256, 1) void gemm_tree(const __hip_bfloat16* __restrict__ A,
                                                    const __hip_bfloat16* __restrict__ Bt,
                                                    const float* __restrict__ th,
                                                    const float* __restrict__ lt,
                                                    const float* __restrict__ resp,
                                                    float* __restrict__ out) {
    __shared__ __align__(16) char smem[36864];   // As 16KB + Bs 20KB; epilogue slab reuses
    __hip_bfloat16* As = (__hip_bfloat16*)smem;            // [128][64]
    __hip_bfloat16* Bs = (__hip_bfloat16*)(smem + 16384);  // [160][64]
    float* E = (float*)smem;                               // [32][161] = 20.6 KB

    const int tid = threadIdx.x;
    const int w = tid >> 6;
    const int l = tid & 63;
    const int m0 = blockIdx.y * 128;      // batch-row base
    const int n0c = blockIdx.x * 160;     // fv-column base
    const int n0t = blockIdx.x * 32;      // tree base
    const int wm = (w & 1) * 64;
    const int wn = (w >> 1) * 80;

    f32x4 acc[4][5] = {};

    const int srow = l >> 3;
    const int schunk = (l & 7) ^ srow;

    for (int kt = 0; kt < 8; ++kt) {
        const int k0 = kt * 64;
#pragma unroll
        for (int q = 0; q < 4; ++q) {     // A: 16 groups of 8 rows
            const int g = q * 4 + w;
            gl2lds16(A + ((size_t)(m0 + g * 8 + srow) * F_DIM + k0 + schunk * 8),
                     As + g * 8 * 64);
        }
#pragma unroll
        for (int q = 0; q < 5; ++q) {     // B: 20 groups of 8 rows
            const int g = q * 4 + w;
            gl2lds16(Bt + ((size_t)(n0c + g * 8 + srow) * F_DIM + k0 + schunk * 8),
                     Bs + g * 8 * 64);
        }
        __syncthreads();

#pragma unroll
        for (int ks = 0; ks < 2; ++ks) {
            bf16x8 af[4], bfr[5];
            const int cb = ks * 4 + (l >> 4);
#pragma unroll
            for (int im = 0; im < 4; ++im) {
                const int r = wm + im * 16 + (l & 15);
                af[im] = *(const bf16x8*)(As + r * 64 + ((cb ^ (r & 7)) * 8));
            }
#pragma unroll
            for (int in = 0; in < 5; ++in) {
                const int r = wn + in * 16 + (l & 15);
                bfr[in] = *(const bf16x8*)(Bs + r * 64 + ((cb ^ (r & 7)) * 8));
            }
#pragma unroll
            for (int im = 0; im < 4; ++im)
#pragma unroll
                for (int in = 0; in < 5; ++in)
                    acc[im][in] = __builtin_amdgcn_mfma_f32_16x16x32_bf16(
                        af[im], bfr[in], acc[im][in], 0, 0, 0);
        }
        __syncthreads();
    }

    // ---- tree epilogue ----
    const int tree = tid & 31;            // local tree 0..31
    const int rg = tid >> 5;              // row-group 0..7 (4 slab rows each)
    const int gt = n0t + tree;            // global tree

    float al[DEPTH], be[DEPTH];
#pragma unroll
    for (int j = 0; j < DEPTH; ++j) {
        const float a = 0.5f * __expf(-lt[gt * DEPTH + j]);
        al[j] = a;
        be[j] = 0.5f - th[gt * DEPTH + j] * a;
    }
    float rs[32];
#pragma unroll
    for (int i = 0; i < 32; ++i) rs[i] = resp[gt * 32 + i];

    const int PAD = 161;
#pragma unroll
    for (int im = 0; im < 4; ++im) {
        // stage this im-pass's 32 rows x 160 cols to LDS
#pragma unroll
        for (int in = 0; in < 5; ++in) {
            const int scol = wn + in * 16 + (l & 15);
#pragma unroll
            for (int r = 0; r < 4; ++r) {
                const int sr = (w & 1) * 16 + (l >> 4) * 4 + r;
                E[sr * PAD + scol] = acc[im][in][r];
            }
        }
        __syncthreads();

#pragma unroll
        for (int rr = 0; rr < 4; ++rr) {
            const int s = rg * 4 + rr;                       // slab row 0..31
            const int gb = m0 + ((s < 16) ? (im * 16 + s) : (64 + im * 16 + (s - 16)));
            const float* f = E + s * PAD + tree * 5;
            float c1[DEPTH];
#pragma unroll
            for (int j = 0; j < DEPTH; ++j) {
                const float v = fmaf(al[j], f[j], be[j]);
                c1[j] = fminf(fmaxf(v, 0.f), 1.f);
            }
            float s16[16], s8[8], s4[4], s2[2];
#pragma unroll
            for (int m = 0; m < 16; ++m) s16[m] = fmaf(c1[0], rs[2*m+1] - rs[2*m], rs[2*m]);
#pragma unroll
            for (int m = 0; m < 8; ++m)  s8[m]  = fmaf(c1[1], s16[2*m+1] - s16[2*m], s16[2*m]);
#pragma unroll
            for (int m = 0; m < 4; ++m)  s4[m]  = fmaf(c1[2], s8[2*m+1] - s8[2*m], s8[2*m]);
#pragma unroll
            for (int m = 0; m < 2; ++m)  s2[m]  = fmaf(c1[3], s4[2*m+1] - s4[2*m], s4[2*m]);
            out[(size_t)gb * NT + gt] = fmaf(c1[4], s2[1] - s2[0], s2[0]);
        }
        __syncthreads();
    }
}

// ---------------------------------------------------------------------------
extern "C" void kernel_launch(void* const* d_in, const int* in_sizes, int n_in,
                              void* d_out, int out_size, void* d_ws, size_t ws_size,
                              hipStream_t stream) {
    const float* x    = (const float*)d_in[0];
    const float* fa   = (const float*)d_in[1];
    const float* th   = (const float*)d_in[2];
    const float* lt   = (const float*)d_in[3];
    const float* resp = (const float*)d_in[4];
    // d_in[5] = path_map: deterministic oblivious layout, hardcoded in epilogue.

    char* ws = (char*)d_ws;
    __hip_bfloat16* Wt = (__hip_bfloat16*)(ws);                 // 2560*512*2 = 2.62 MB
    __hip_bfloat16* Xb = (__hip_bfloat16*)(ws + (4u << 20));    // 2048*512*2 = 2.10 MB
    float* out = (float*)d_out;

    hipLaunchKernelGGL(prep, dim3(1024 + 160), dim3(256), 0, stream, x, fa, Xb, Wt);
    hipLaunchKernelGGL(gemm_tree, dim3(NCOL / 160, BATCH / 128), dim3(256), 0, stream,
                       Xb, Wt, th, lt, resp, out);
}